// Round 3
// baseline (200.419 us; speedup 1.0000x reference)
//
#include <hip/hip_runtime.h>
#include <hip/hip_bf16.h>
#include <math.h>

#define BATCH 4096
#define DIM   2048
#define INV_T 2.0f   // 1 / TEMPERATURE, TEMPERATURE = 0.5

#define BM 128
#define BN 128

typedef float floatx4 __attribute__((ext_vector_type(4)));
typedef int   intx4   __attribute__((ext_vector_type(4)));
typedef int   intx8   __attribute__((ext_vector_type(8)));

static __device__ __forceinline__ void gld_lds16(const void* g, void* l) {
  __builtin_amdgcn_global_load_lds(
      (const __attribute__((address_space(1))) void*)g,
      (__attribute__((address_space(3))) void*)l, 16, 0, 0);
}

static __device__ __forceinline__ intx8 comb8(intx4 lo, intx4 hi) {
  intx8 r;
  r[0] = lo[0]; r[1] = lo[1]; r[2] = lo[2]; r[3] = lo[3];
  r[4] = hi[0]; r[5] = hi[1]; r[6] = hi[2]; r[7] = hi[3];
  return r;
}

// ---------------------------------------------------------------------------
// Kernel 1: per-row log-softmax prep. Wave-per-row, NO barriers.
//   rows [0, B)  -> Li8 = fp8_e4m3(log_softmax(c_i))
//   rows [B, 2B) -> Qb8 = fp8_e4m3(softmax(c_j) * 2^t_j)  (per-row pow2 scale
//                   so max lands ~[128,256): avoids e4m3 underflow)
//                   + hneg fp32 (from EXACT fp32 Q) + isc = 2^-t + rowsum = 0
// ---------------------------------------------------------------------------
__global__ __launch_bounds__(256) void prep_kernel(
    const float* __restrict__ ci, const float* __restrict__ cj,
    unsigned char* __restrict__ Li8, unsigned char* __restrict__ Qb8,
    float* __restrict__ hneg, float* __restrict__ isc,
    float* __restrict__ rowsum, float* __restrict__ out)
{
  const int lane = threadIdx.x & 63;
  const int wave = threadIdx.x >> 6;
  const int row = blockIdx.x * 4 + wave;
  const bool isj = row >= BATCH;
  const int r = isj ? row - BATCH : row;
  const float* __restrict__ src = (isj ? cj : ci) + (size_t)r * DIM;

  // 32 elements per lane: float4 chunks at [i*64 + lane], i = 0..7
  float v[32];
  #pragma unroll
  for (int i = 0; i < 8; ++i) {
    float4 t = ((const float4*)src)[i * 64 + lane];
    v[i * 4 + 0] = t.x; v[i * 4 + 1] = t.y;
    v[i * 4 + 2] = t.z; v[i * 4 + 3] = t.w;
  }

  // wave max
  float m = v[0];
  #pragma unroll
  for (int i = 1; i < 32; ++i) m = fmaxf(m, v[i]);
  #pragma unroll
  for (int off = 32; off >= 1; off >>= 1) m = fmaxf(m, __shfl_xor(m, off));

  // wave sum of exp(v - m)
  float s = 0.f;
  #pragma unroll
  for (int i = 0; i < 32; ++i) s += __expf(v[i] - m);
  #pragma unroll
  for (int off = 32; off >= 1; off >>= 1) s += __shfl_xor(s, off);
  const float ls = m + __logf(s);          // logsumexp of row

  // per-row pow2 scale for Q rows: Qmax = exp(m - ls); want Qmax*2^t in [128,256)
  float scale = 1.f;
  int t = 0;
  if (isj) {
    const float qmax = __expf(m - ls);
    int e;
    (void)frexpf(qmax, &e);               // qmax = f * 2^e, f in [0.5, 1)
    t = 8 - e;
    scale = ldexpf(1.f, t);
  }

  unsigned char* dst = (isj ? Qb8 : Li8) + (size_t)r * DIM;
  float h = 0.f;
  #pragma unroll
  for (int i = 0; i < 8; ++i) {
    float f[4];
    #pragma unroll
    for (int j = 0; j < 4; ++j) {
      const float li = v[i * 4 + j] - ls;  // log_softmax element
      if (isj) {
        const float q = __expf(li);        // exact softmax element
        h += q * li;                       // negative entropy (fp32, exact Q)
        f[j] = q * scale;
      } else {
        f[j] = li;
      }
    }
    int w = __builtin_amdgcn_cvt_pk_fp8_f32(f[0], f[1], 0, false);
    w = __builtin_amdgcn_cvt_pk_fp8_f32(f[2], f[3], w, true);
    ((int*)dst)[i * 64 + lane] = w;        // bytes (i*256 + lane*4) ..+3
  }

  if (isj) {
    #pragma unroll
    for (int off = 32; off >= 1; off >>= 1) h += __shfl_xor(h, off);
    if (lane == 0) {
      hneg[r] = h;
      isc[r] = ldexpf(1.f, -t);
      rowsum[r] = 0.f;
    }
  }
  if (row == 0 && lane == 0) out[0] = 0.f;
}

// ---------------------------------------------------------------------------
// Kernel 2: cross' = Li8 @ Qb8^T via MX-fp8 MFMA (16x16x128, scale=1.0),
// 128x128 tile, K-panel = 128 bytes. XOR-swizzled LDS (chunk c ^ (row&7))
// satisfies global_load_lds linear-dest AND gives <=2-way bank aliasing on
// the frag ds_read_b128s. Epilogue un-scales per column (cross = acc*isc[j])
// then: rowsum[i] += sum_j exp(INV_T*(cross - hneg[j])); diag on bx==by.
// Safe without max-subtraction: KL >= 0 => logits <= ~0.
// ---------------------------------------------------------------------------
__global__ __launch_bounds__(256) void gemm_lse_kernel(
    const unsigned char* __restrict__ Li8, const unsigned char* __restrict__ Qb8,
    const float* __restrict__ hneg, const float* __restrict__ isc,
    float* __restrict__ rowsum, float* __restrict__ diag)
{
  __shared__ __attribute__((aligned(16))) unsigned char As[BM * 128]; // 16 KB
  __shared__ __attribute__((aligned(16))) unsigned char Bs[BN * 128]; // 16 KB

  const int tid  = threadIdx.x;
  const int bx   = blockIdx.x;             // N tile index
  const int by   = blockIdx.y;             // M tile index
  const int lane = tid & 63;
  const int wave = tid >> 6;
  const int wm   = (wave >> 1) * 64;       // wave row offset within tile
  const int wn   = (wave & 1) * 64;        // wave col offset within tile

  // staging: 1024 16B-chunks per operand-tile; thread t does chunks t+256*s.
  // LDS chunk p holds global chunk (row = p>>3, cb = (p&7) ^ (row&7)).
  const unsigned char* gA[4];
  const unsigned char* gB[4];
  #pragma unroll
  for (int s = 0; s < 4; ++s) {
    const int p = tid + 256 * s;
    const int row = p >> 3;
    const int cbg = (p & 7) ^ (row & 7);
    gA[s] = Li8 + (size_t)(by * BM + row) * DIM + cbg * 16;
    gB[s] = Qb8 + (size_t)(bx * BN + row) * DIM + cbg * 16;
  }

  const int rl = lane & 15;                // m/n within frag; col within C/D
  const int q  = lane >> 4;                // k-quad: k in [q*32, q*32+32)
  const int sw = rl & 7;                   // XOR swizzle key (row & 7)

  floatx4 acc[4][4];
  const floatx4 z = {0.f, 0.f, 0.f, 0.f};
  #pragma unroll
  for (int mt = 0; mt < 4; ++mt)
    #pragma unroll
    for (int nt = 0; nt < 4; ++nt) acc[mt][nt] = z;

  for (int k = 0; k < DIM; k += 128) {
    #pragma unroll
    for (int s = 0; s < 4; ++s) {
      gld_lds16(gA[s] + k, As + (tid + 256 * s) * 16);
      gld_lds16(gB[s] + k, Bs + (tid + 256 * s) * 16);
    }
    __syncthreads();   // drains vmcnt before barrier

    intx8 af[4], bf[4];
    #pragma unroll
    for (int t = 0; t < 4; ++t) {
      const int ra = wm + t * 16 + rl;
      const int p0 = ra * 8 + ((2 * q) ^ sw);
      const int p1 = ra * 8 + ((2 * q + 1) ^ sw);
      af[t] = comb8(*(const intx4*)(As + p0 * 16), *(const intx4*)(As + p1 * 16));
      const int rb = wn + t * 16 + rl;
      const int q0 = rb * 8 + ((2 * q) ^ sw);
      const int q1 = rb * 8 + ((2 * q + 1) ^ sw);
      bf[t] = comb8(*(const intx4*)(Bs + q0 * 16), *(const intx4*)(Bs + q1 * 16));
    }
    #pragma unroll
    for (int mt = 0; mt < 4; ++mt)
      #pragma unroll
      for (int nt = 0; nt < 4; ++nt)
        acc[mt][nt] = __builtin_amdgcn_mfma_scale_f32_16x16x128_f8f6f4(
            af[mt], bf[nt], acc[mt][nt],
            0, 0,            // cbsz = fp8(e4m3), blgp = fp8(e4m3)
            0, 127,          // scale A: opsel 0, e8m0 127 = 1.0
            0, 127);         // scale B: 1.0
    __syncthreads();
  }

  // ---- epilogue. C/D layout: col = lane&15, row = (lane>>4)*4 + reg ----
  const int col0 = bx * BN + wn + rl;
  float hn[4], sc[4];
  #pragma unroll
  for (int nt = 0; nt < 4; ++nt) {
    hn[nt] = hneg[col0 + nt * 16];
    sc[nt] = isc[col0 + nt * 16];
  }
  const int row0 = by * BM + wm + (q << 2);

  // diag: frag (mt,mt), reg rr = rl-4*q, lanes with q == rl>>2 (col==row here)
  if (bx == by && wm == wn && q == (rl >> 2)) {
    #pragma unroll
    for (int mt = 0; mt < 4; ++mt)
      diag[by * BM + wm + mt * 16 + rl] = acc[mt][mt][rl & 3] * sc[mt];
  }

  #pragma unroll
  for (int mt = 0; mt < 4; ++mt) {
    #pragma unroll
    for (int rr = 0; rr < 4; ++rr) {
      float p = 0.f;
      #pragma unroll
      for (int nt = 0; nt < 4; ++nt)
        p += __expf(INV_T * (acc[mt][nt][rr] * sc[nt] - hn[nt]));
      // reduce across 16 cols (lane&15 group)
      p += __shfl_xor(p, 1);
      p += __shfl_xor(p, 2);
      p += __shfl_xor(p, 4);
      p += __shfl_xor(p, 8);
      if (rl == 0)
        atomicAdd(&rowsum[row0 + mt * 16 + rr], p);
    }
  }
}

// ---------------------------------------------------------------------------
// Kernel 3: loss = (1/B) sum_i [ log(rowsum[i]) - INV_T*(diag[i] - hneg[i]) ]
// ---------------------------------------------------------------------------
__global__ __launch_bounds__(256) void finalize_kernel(
    const float* __restrict__ hneg, const float* __restrict__ rowsum,
    const float* __restrict__ diag, float* __restrict__ out)
{
  const int i = blockIdx.x * 256 + threadIdx.x;
  const int lane = threadIdx.x & 63;
  const int wave = threadIdx.x >> 6;

  float c = __logf(rowsum[i]) - INV_T * (diag[i] - hneg[i]);
  #pragma unroll
  for (int off = 32; off >= 1; off >>= 1) c += __shfl_xor(c, off);

  __shared__ float red[4];
  if (lane == 0) red[wave] = c;
  __syncthreads();
  if (threadIdx.x == 0)
    atomicAdd(out, (red[0] + red[1] + red[2] + red[3]) * (1.0f / BATCH));
}

// ---------------------------------------------------------------------------
extern "C" void kernel_launch(void* const* d_in, const int* in_sizes, int n_in,
                              void* d_out, int out_size, void* d_ws, size_t ws_size,
                              hipStream_t stream) {
  const float* ci = (const float*)d_in[0];
  const float* cj = (const float*)d_in[1];
  float* out = (float*)d_out;

  // ws: Li8 u8[B*D] | Qb8 u8[B*D] | hneg f32[B] | isc f32[B] | rowsum f32[B] | diag f32[B]
  unsigned char* Li8 = (unsigned char*)d_ws;
  unsigned char* Qb8 = Li8 + (size_t)BATCH * DIM;
  float* hneg   = (float*)(Qb8 + (size_t)BATCH * DIM);
  float* isc    = hneg + BATCH;
  float* rowsum = isc + BATCH;
  float* diag   = rowsum + BATCH;

  prep_kernel<<<2 * BATCH / 4, 256, 0, stream>>>(ci, cj, Li8, Qb8, hneg, isc, rowsum, out);
  dim3 grid(BATCH / BN, BATCH / BM);
  gemm_lse_kernel<<<grid, 256, 0, stream>>>(Li8, Qb8, hneg, isc, rowsum, diag);
  finalize_kernel<<<BATCH / 256, 256, 0, stream>>>(hneg, rowsum, diag, out);
}

// Round 4
// 149.036 us; speedup vs baseline: 1.3448x; 1.3448x over previous
//
#include <hip/hip_runtime.h>
#include <hip/hip_bf16.h>
#include <math.h>

#define BATCH 4096
#define DIM   2048
#define INV_T 2.0f   // 1 / TEMPERATURE, TEMPERATURE = 0.5

#define BM 128
#define BN 128

typedef float floatx4 __attribute__((ext_vector_type(4)));
typedef int   intx4   __attribute__((ext_vector_type(4)));
typedef int   intx8   __attribute__((ext_vector_type(8)));

static __device__ __forceinline__ void gld_lds16(const void* g, void* l) {
  __builtin_amdgcn_global_load_lds(
      (const __attribute__((address_space(1))) void*)g,
      (__attribute__((address_space(3))) void*)l, 16, 0, 0);
}

static __device__ __forceinline__ intx8 comb8(intx4 lo, intx4 hi) {
  intx8 r;
  r[0] = lo[0]; r[1] = lo[1]; r[2] = lo[2]; r[3] = lo[3];
  r[4] = hi[0]; r[5] = hi[1]; r[6] = hi[2]; r[7] = hi[3];
  return r;
}

// ---------------------------------------------------------------------------
// Kernel 1: per-row log-softmax prep. Wave-per-row, NO barriers.
//   rows [0, B)  -> Li8 = fp8_e4m3(log_softmax(c_i))
//   rows [B, 2B) -> Qb8 = fp8_e4m3(softmax(c_j) * 2^t_j)  (per-row pow2 scale
//                   so max lands ~[128,256): avoids e4m3 underflow)
//                   + hneg fp32 (from EXACT fp32 Q) + isc = 2^-t + rowsum = 0
// ---------------------------------------------------------------------------
__global__ __launch_bounds__(256) void prep_kernel(
    const float* __restrict__ ci, const float* __restrict__ cj,
    unsigned char* __restrict__ Li8, unsigned char* __restrict__ Qb8,
    float* __restrict__ hneg, float* __restrict__ isc,
    float* __restrict__ rowsum, float* __restrict__ out)
{
  const int lane = threadIdx.x & 63;
  const int wave = threadIdx.x >> 6;
  const int row = blockIdx.x * 4 + wave;
  const bool isj = row >= BATCH;
  const int r = isj ? row - BATCH : row;
  const float* __restrict__ src = (isj ? cj : ci) + (size_t)r * DIM;

  // 32 elements per lane: float4 chunks at [i*64 + lane], i = 0..7
  float v[32];
  #pragma unroll
  for (int i = 0; i < 8; ++i) {
    float4 t = ((const float4*)src)[i * 64 + lane];
    v[i * 4 + 0] = t.x; v[i * 4 + 1] = t.y;
    v[i * 4 + 2] = t.z; v[i * 4 + 3] = t.w;
  }

  // wave max
  float m = v[0];
  #pragma unroll
  for (int i = 1; i < 32; ++i) m = fmaxf(m, v[i]);
  #pragma unroll
  for (int off = 32; off >= 1; off >>= 1) m = fmaxf(m, __shfl_xor(m, off));

  // wave sum of exp(v - m)
  float s = 0.f;
  #pragma unroll
  for (int i = 0; i < 32; ++i) s += __expf(v[i] - m);
  #pragma unroll
  for (int off = 32; off >= 1; off >>= 1) s += __shfl_xor(s, off);
  const float ls = m + __logf(s);          // logsumexp of row

  // per-row pow2 scale for Q rows: Qmax = exp(m - ls); want Qmax*2^t in [128,256)
  float scale = 1.f;
  int t = 0;
  if (isj) {
    const float qmax = __expf(m - ls);
    const int be = (int)((__float_as_uint(qmax) >> 23) & 0xff);
    t = 134 - be;                          // qmax*2^t in [128,256)
    scale = __uint_as_float((unsigned)(t + 127) << 23);
  }

  unsigned char* dst = (isj ? Qb8 : Li8) + (size_t)r * DIM;
  float h = 0.f;
  #pragma unroll
  for (int i = 0; i < 8; ++i) {
    float f[4];
    #pragma unroll
    for (int j = 0; j < 4; ++j) {
      const float li = v[i * 4 + j] - ls;  // log_softmax element
      if (isj) {
        const float q = __expf(li);        // exact softmax element
        h += q * li;                       // negative entropy (fp32, exact Q)
        f[j] = q * scale;
      } else {
        f[j] = li;
      }
    }
    int w = __builtin_amdgcn_cvt_pk_fp8_f32(f[0], f[1], 0, false);
    w = __builtin_amdgcn_cvt_pk_fp8_f32(f[2], f[3], w, true);
    ((int*)dst)[i * 64 + lane] = w;        // bytes (i*256 + lane*4) ..+3
  }

  if (isj) {
    #pragma unroll
    for (int off = 32; off >= 1; off >>= 1) h += __shfl_xor(h, off);
    if (lane == 0) {
      hneg[r] = h;
      isc[r] = __uint_as_float((unsigned)(127 - t) << 23);  // 2^-t
      rowsum[r] = 0.f;
    }
  }
  if (row == 0 && lane == 0) out[0] = 0.f;
}

// ---------------------------------------------------------------------------
// Kernel 2: cross' = Li8 @ Qb8^T via MX-fp8 MFMA (16x16x128, scale=1.0),
// 128x128 tile, K-panel = 128 bytes. XOR-swizzled LDS (chunk c ^ (row&7)).
// Register discipline (R3 spilled at 256 VGPR): preload bf[4] (32 VGPR),
// STREAM af one at a time (8 VGPR); __launch_bounds__(256,3) caps at ~168.
// Epilogue un-scales per column, rowsum/diag as before.
// ---------------------------------------------------------------------------
__global__ __launch_bounds__(256, 3) void gemm_lse_kernel(
    const unsigned char* __restrict__ Li8, const unsigned char* __restrict__ Qb8,
    const float* __restrict__ hneg, const float* __restrict__ isc,
    float* __restrict__ rowsum, float* __restrict__ diag)
{
  __shared__ __attribute__((aligned(16))) unsigned char As[BM * 128]; // 16 KB
  __shared__ __attribute__((aligned(16))) unsigned char Bs[BN * 128]; // 16 KB

  const int tid  = threadIdx.x;
  const int bx   = blockIdx.x;             // N tile index
  const int by   = blockIdx.y;             // M tile index
  const int lane = tid & 63;
  const int wave = tid >> 6;
  const int wm   = (wave >> 1) * 64;       // wave row offset within tile
  const int wn   = (wave & 1) * 64;        // wave col offset within tile

  // staging: 1024 16B-chunks per operand-tile; thread t does chunks t+256*s.
  // LDS chunk p holds global chunk (row = p>>3, cb = (p&7) ^ (row&7)).
  // Same byte offset for A and B -> one offset array, two bases.
  int soff[4];
  #pragma unroll
  for (int s = 0; s < 4; ++s) {
    const int p = tid + 256 * s;
    const int row = p >> 3;
    const int cbg = (p & 7) ^ (row & 7);
    soff[s] = row * DIM + cbg * 16;
  }
  const unsigned char* Abase = Li8 + (size_t)(by * BM) * DIM;
  const unsigned char* Bbase = Qb8 + (size_t)(bx * BN) * DIM;

  const int rl = lane & 15;                // m/n within frag; col within C/D
  const int q  = lane >> 4;                // k-quad: k in [q*32, q*32+32)
  const int sw = rl & 7;                   // XOR swizzle key (row & 7)

  floatx4 acc[4][4];
  const floatx4 z = {0.f, 0.f, 0.f, 0.f};
  #pragma unroll
  for (int mt = 0; mt < 4; ++mt)
    #pragma unroll
    for (int nt = 0; nt < 4; ++nt) acc[mt][nt] = z;

  for (int k = 0; k < DIM; k += 128) {
    #pragma unroll
    for (int s = 0; s < 4; ++s) {
      gld_lds16(Abase + soff[s] + k, As + (tid + 256 * s) * 16);
      gld_lds16(Bbase + soff[s] + k, Bs + (tid + 256 * s) * 16);
    }
    __syncthreads();   // drains vmcnt before barrier

    // preload all 4 B fragments (reused by every mt) -- 32 VGPRs
    intx8 bf[4];
    #pragma unroll
    for (int t = 0; t < 4; ++t) {
      const int rb = wn + t * 16 + rl;
      const int q0 = rb * 8 + ((2 * q) ^ sw);
      const int q1 = rb * 8 + ((2 * q + 1) ^ sw);
      bf[t] = comb8(*(const intx4*)(Bs + q0 * 16), *(const intx4*)(Bs + q1 * 16));
    }
    // stream A fragments one at a time -- 8 VGPRs live
    #pragma unroll
    for (int mt = 0; mt < 4; ++mt) {
      const int ra = wm + mt * 16 + rl;
      const int p0 = ra * 8 + ((2 * q) ^ sw);
      const int p1 = ra * 8 + ((2 * q + 1) ^ sw);
      const intx8 af = comb8(*(const intx4*)(As + p0 * 16),
                             *(const intx4*)(As + p1 * 16));
      #pragma unroll
      for (int nt = 0; nt < 4; ++nt)
        acc[mt][nt] = __builtin_amdgcn_mfma_scale_f32_16x16x128_f8f6f4(
            af, bf[nt], acc[mt][nt],
            0, 0,            // cbsz = fp8(e4m3), blgp = fp8(e4m3)
            0, 127,          // scale A: opsel 0, e8m0 127 = 1.0
            0, 127);         // scale B: 1.0
    }
    __syncthreads();
  }

  // ---- epilogue. C/D layout: col = lane&15, row = (lane>>4)*4 + reg ----
  const int col0 = bx * BN + wn + rl;
  float hn[4], sc[4];
  #pragma unroll
  for (int nt = 0; nt < 4; ++nt) {
    hn[nt] = hneg[col0 + nt * 16];
    sc[nt] = isc[col0 + nt * 16];
  }
  const int row0 = by * BM + wm + (q << 2);

  // diag: frag (mt,mt), reg rr = rl-4*q, lanes with q == rl>>2 (col==row here)
  if (bx == by && wm == wn && q == (rl >> 2)) {
    #pragma unroll
    for (int mt = 0; mt < 4; ++mt)
      diag[by * BM + wm + mt * 16 + rl] = acc[mt][mt][rl & 3] * sc[mt];
  }

  #pragma unroll
  for (int mt = 0; mt < 4; ++mt) {
    #pragma unroll
    for (int rr = 0; rr < 4; ++rr) {
      float p = 0.f;
      #pragma unroll
      for (int nt = 0; nt < 4; ++nt)
        p += __expf(INV_T * (acc[mt][nt][rr] * sc[nt] - hn[nt]));
      // reduce across 16 cols (lane&15 group)
      p += __shfl_xor(p, 1);
      p += __shfl_xor(p, 2);
      p += __shfl_xor(p, 4);
      p += __shfl_xor(p, 8);
      if (rl == 0)
        atomicAdd(&rowsum[row0 + mt * 16 + rr], p);
    }
  }
}

// ---------------------------------------------------------------------------
// Kernel 3: loss = (1/B) sum_i [ log(rowsum[i]) - INV_T*(diag[i] - hneg[i]) ]
// ---------------------------------------------------------------------------
__global__ __launch_bounds__(256) void finalize_kernel(
    const float* __restrict__ hneg, const float* __restrict__ rowsum,
    const float* __restrict__ diag, float* __restrict__ out)
{
  const int i = blockIdx.x * 256 + threadIdx.x;
  const int lane = threadIdx.x & 63;
  const int wave = threadIdx.x >> 6;

  float c = __logf(rowsum[i]) - INV_T * (diag[i] - hneg[i]);
  #pragma unroll
  for (int off = 32; off >= 1; off >>= 1) c += __shfl_xor(c, off);

  __shared__ float red[4];
  if (lane == 0) red[wave] = c;
  __syncthreads();
  if (threadIdx.x == 0)
    atomicAdd(out, (red[0] + red[1] + red[2] + red[3]) * (1.0f / BATCH));
}

// ---------------------------------------------------------------------------
extern "C" void kernel_launch(void* const* d_in, const int* in_sizes, int n_in,
                              void* d_out, int out_size, void* d_ws, size_t ws_size,
                              hipStream_t stream) {
  const float* ci = (const float*)d_in[0];
  const float* cj = (const float*)d_in[1];
  float* out = (float*)d_out;

  // ws: Li8 u8[B*D] | Qb8 u8[B*D] | hneg f32[B] | isc f32[B] | rowsum f32[B] | diag f32[B]
  unsigned char* Li8 = (unsigned char*)d_ws;
  unsigned char* Qb8 = Li8 + (size_t)BATCH * DIM;
  float* hneg   = (float*)(Qb8 + (size_t)BATCH * DIM);
  float* isc    = hneg + BATCH;
  float* rowsum = isc + BATCH;
  float* diag   = rowsum + BATCH;

  prep_kernel<<<2 * BATCH / 4, 256, 0, stream>>>(ci, cj, Li8, Qb8, hneg, isc, rowsum, out);
  dim3 grid(BATCH / BN, BATCH / BM);
  gemm_lse_kernel<<<grid, 256, 0, stream>>>(Li8, Qb8, hneg, isc, rowsum, diag);
  finalize_kernel<<<BATCH / 256, 256, 0, stream>>>(hneg, rowsum, diag, out);
}

// Round 5
// 148.404 us; speedup vs baseline: 1.3505x; 1.0043x over previous
//
#include <hip/hip_runtime.h>
#include <hip/hip_bf16.h>
#include <math.h>

#define BATCH 4096
#define DIM   2048
#define INV_T 2.0f   // 1 / TEMPERATURE, TEMPERATURE = 0.5

#define BM 128
#define BN 128

typedef float floatx4 __attribute__((ext_vector_type(4)));
typedef int   intx4   __attribute__((ext_vector_type(4)));
typedef int   intx8   __attribute__((ext_vector_type(8)));

static __device__ __forceinline__ void gld_lds16(const void* g, void* l) {
  __builtin_amdgcn_global_load_lds(
      (const __attribute__((address_space(1))) void*)g,
      (__attribute__((address_space(3))) void*)l, 16, 0, 0);
}

static __device__ __forceinline__ intx8 comb8(intx4 lo, intx4 hi) {
  intx8 r;
  r[0] = lo[0]; r[1] = lo[1]; r[2] = lo[2]; r[3] = lo[3];
  r[4] = hi[0]; r[5] = hi[1]; r[6] = hi[2]; r[7] = hi[3];
  return r;
}

// ---------------------------------------------------------------------------
// Kernel 1: per-row log-softmax prep. Wave-per-row, NO barriers.
//   rows [0, B)  -> Li8 = fp8_e4m3(log_softmax(c_i))
//   rows [B, 2B) -> Qb8 = fp8_e4m3(softmax(c_j) * 2^t_j)  (per-row pow2 scale
//                   so max lands ~[128,256): avoids e4m3 underflow)
//                   + hneg fp32 (from EXACT fp32 Q) + isc = 2^-t + rowsum = 0
// ---------------------------------------------------------------------------
__global__ __launch_bounds__(256) void prep_kernel(
    const float* __restrict__ ci, const float* __restrict__ cj,
    unsigned char* __restrict__ Li8, unsigned char* __restrict__ Qb8,
    float* __restrict__ hneg, float* __restrict__ isc,
    float* __restrict__ rowsum, float* __restrict__ out)
{
  const int lane = threadIdx.x & 63;
  const int wave = threadIdx.x >> 6;
  const int row = blockIdx.x * 4 + wave;
  const bool isj = row >= BATCH;
  const int r = isj ? row - BATCH : row;
  const float* __restrict__ src = (isj ? cj : ci) + (size_t)r * DIM;

  // 32 elements per lane: float4 chunks at [i*64 + lane], i = 0..7
  float v[32];
  #pragma unroll
  for (int i = 0; i < 8; ++i) {
    float4 t = ((const float4*)src)[i * 64 + lane];
    v[i * 4 + 0] = t.x; v[i * 4 + 1] = t.y;
    v[i * 4 + 2] = t.z; v[i * 4 + 3] = t.w;
  }

  // wave max
  float m = v[0];
  #pragma unroll
  for (int i = 1; i < 32; ++i) m = fmaxf(m, v[i]);
  #pragma unroll
  for (int off = 32; off >= 1; off >>= 1) m = fmaxf(m, __shfl_xor(m, off));

  // wave sum of exp(v - m)
  float s = 0.f;
  #pragma unroll
  for (int i = 0; i < 32; ++i) s += __expf(v[i] - m);
  #pragma unroll
  for (int off = 32; off >= 1; off >>= 1) s += __shfl_xor(s, off);
  const float ls = m + __logf(s);          // logsumexp of row

  // per-row pow2 scale for Q rows: Qmax = exp(m - ls); want Qmax*2^t in [128,256)
  float scale = 1.f;
  int t = 0;
  if (isj) {
    const float qmax = __expf(m - ls);
    const int be = (int)((__float_as_uint(qmax) >> 23) & 0xff);
    t = 134 - be;                          // qmax*2^t in [128,256)
    scale = __uint_as_float((unsigned)(t + 127) << 23);
  }

  unsigned char* dst = (isj ? Qb8 : Li8) + (size_t)r * DIM;
  float h = 0.f;
  #pragma unroll
  for (int i = 0; i < 8; ++i) {
    float f[4];
    #pragma unroll
    for (int j = 0; j < 4; ++j) {
      const float li = v[i * 4 + j] - ls;  // log_softmax element
      if (isj) {
        const float q = __expf(li);        // exact softmax element
        h += q * li;                       // negative entropy (fp32, exact Q)
        f[j] = q * scale;
      } else {
        f[j] = li;
      }
    }
    int w = __builtin_amdgcn_cvt_pk_fp8_f32(f[0], f[1], 0, false);
    w = __builtin_amdgcn_cvt_pk_fp8_f32(f[2], f[3], w, true);
    ((int*)dst)[i * 64 + lane] = w;        // bytes (i*256 + lane*4) ..+3
  }

  if (isj) {
    #pragma unroll
    for (int off = 32; off >= 1; off >>= 1) h += __shfl_xor(h, off);
    if (lane == 0) {
      hneg[r] = h;
      isc[r] = __uint_as_float((unsigned)(127 - t) << 23);  // 2^-t
      rowsum[r] = 0.f;
    }
  }
  if (row == 0 && lane == 0) out[0] = 0.f;
}

// ---------------------------------------------------------------------------
// Kernel 2: cross' = Li8 @ Qb8^T via MX-fp8 MFMA (16x16x128, scale=1.0),
// 128x128 tile, XOR-swizzled LDS. R5: XCD-aware tile swizzle — 1D grid,
// XCD c = lin&7 owns bx in [4c, 4c+4) so its B working set (1 MB) stays
// L2-resident; dispatch-adjacent s share by so A-tiles hit L2 too.
// (R4 analysis: staging 512 MB from L2/L3 at 8.9 TB/s was the wall.)
// ---------------------------------------------------------------------------
__global__ __launch_bounds__(256, 3) void gemm_lse_kernel(
    const unsigned char* __restrict__ Li8, const unsigned char* __restrict__ Qb8,
    const float* __restrict__ hneg, const float* __restrict__ isc,
    float* __restrict__ rowsum, float* __restrict__ diag)
{
  __shared__ __attribute__((aligned(16))) unsigned char As[BM * 128]; // 16 KB
  __shared__ __attribute__((aligned(16))) unsigned char Bs[BN * 128]; // 16 KB

  const int tid  = threadIdx.x;
  // XCD-aware swizzle: lin%8 = XCD (round-robin heuristic). bx = 4*xcd + s%4.
  const int lin = blockIdx.x;
  const int xc  = lin & 7;
  const int sq  = lin >> 3;
  const int bx  = (xc << 2) | (sq & 3);    // N tile index
  const int by  = sq >> 2;                 // M tile index
  const int lane = tid & 63;
  const int wave = tid >> 6;
  const int wm   = (wave >> 1) * 64;       // wave row offset within tile
  const int wn   = (wave & 1) * 64;        // wave col offset within tile

  // staging: 1024 16B-chunks per operand-tile; thread t does chunks t+256*s.
  // LDS chunk p holds global chunk (row = p>>3, cb = (p&7) ^ (row&7)).
  int soff[4];
  #pragma unroll
  for (int s = 0; s < 4; ++s) {
    const int p = tid + 256 * s;
    const int row = p >> 3;
    const int cbg = (p & 7) ^ (row & 7);
    soff[s] = row * DIM + cbg * 16;
  }
  const unsigned char* Abase = Li8 + (size_t)(by * BM) * DIM;
  const unsigned char* Bbase = Qb8 + (size_t)(bx * BN) * DIM;

  const int rl = lane & 15;                // m/n within frag; col within C/D
  const int q  = lane >> 4;                // k-quad: k in [q*32, q*32+32)
  const int sw = rl & 7;                   // XOR swizzle key (row & 7)

  floatx4 acc[4][4];
  const floatx4 z = {0.f, 0.f, 0.f, 0.f};
  #pragma unroll
  for (int mt = 0; mt < 4; ++mt)
    #pragma unroll
    for (int nt = 0; nt < 4; ++nt) acc[mt][nt] = z;

  for (int k = 0; k < DIM; k += 128) {
    #pragma unroll
    for (int s = 0; s < 4; ++s) {
      gld_lds16(Abase + soff[s] + k, As + (tid + 256 * s) * 16);
      gld_lds16(Bbase + soff[s] + k, Bs + (tid + 256 * s) * 16);
    }
    __syncthreads();   // drains vmcnt before barrier

    // preload all 4 B fragments (reused by every mt) -- 32 VGPRs
    intx8 bf[4];
    #pragma unroll
    for (int t = 0; t < 4; ++t) {
      const int rb = wn + t * 16 + rl;
      const int q0 = rb * 8 + ((2 * q) ^ sw);
      const int q1 = rb * 8 + ((2 * q + 1) ^ sw);
      bf[t] = comb8(*(const intx4*)(Bs + q0 * 16), *(const intx4*)(Bs + q1 * 16));
    }
    // stream A fragments one at a time -- 8 VGPRs live
    #pragma unroll
    for (int mt = 0; mt < 4; ++mt) {
      const int ra = wm + mt * 16 + rl;
      const int p0 = ra * 8 + ((2 * q) ^ sw);
      const int p1 = ra * 8 + ((2 * q + 1) ^ sw);
      const intx8 af = comb8(*(const intx4*)(As + p0 * 16),
                             *(const intx4*)(As + p1 * 16));
      #pragma unroll
      for (int nt = 0; nt < 4; ++nt)
        acc[mt][nt] = __builtin_amdgcn_mfma_scale_f32_16x16x128_f8f6f4(
            af, bf[nt], acc[mt][nt],
            0, 0,            // cbsz = fp8(e4m3), blgp = fp8(e4m3)
            0, 127,          // scale A: opsel 0, e8m0 127 = 1.0
            0, 127);         // scale B: 1.0
    }
    __syncthreads();
  }

  // ---- epilogue. C/D layout: col = lane&15, row = (lane>>4)*4 + reg ----
  const int col0 = bx * BN + wn + rl;
  float hn[4], sc[4];
  #pragma unroll
  for (int nt = 0; nt < 4; ++nt) {
    hn[nt] = hneg[col0 + nt * 16];
    sc[nt] = isc[col0 + nt * 16];
  }
  const int row0 = by * BM + wm + (q << 2);

  // diag: frag (mt,mt), reg rr = rl-4*q, lanes with q == rl>>2 (col==row here)
  if (bx == by && wm == wn && q == (rl >> 2)) {
    #pragma unroll
    for (int mt = 0; mt < 4; ++mt)
      diag[by * BM + wm + mt * 16 + rl] = acc[mt][mt][rl & 3] * sc[mt];
  }

  #pragma unroll
  for (int mt = 0; mt < 4; ++mt) {
    #pragma unroll
    for (int rr = 0; rr < 4; ++rr) {
      float p = 0.f;
      #pragma unroll
      for (int nt = 0; nt < 4; ++nt)
        p += __expf(INV_T * (acc[mt][nt][rr] * sc[nt] - hn[nt]));
      // reduce across 16 cols (lane&15 group)
      p += __shfl_xor(p, 1);
      p += __shfl_xor(p, 2);
      p += __shfl_xor(p, 4);
      p += __shfl_xor(p, 8);
      if (rl == 0)
        atomicAdd(&rowsum[row0 + mt * 16 + rr], p);
    }
  }
}

// ---------------------------------------------------------------------------
// Kernel 3: loss = (1/B) sum_i [ log(rowsum[i]) - INV_T*(diag[i] - hneg[i]) ]
// ---------------------------------------------------------------------------
__global__ __launch_bounds__(256) void finalize_kernel(
    const float* __restrict__ hneg, const float* __restrict__ rowsum,
    const float* __restrict__ diag, float* __restrict__ out)
{
  const int i = blockIdx.x * 256 + threadIdx.x;
  const int lane = threadIdx.x & 63;
  const int wave = threadIdx.x >> 6;

  float c = __logf(rowsum[i]) - INV_T * (diag[i] - hneg[i]);
  #pragma unroll
  for (int off = 32; off >= 1; off >>= 1) c += __shfl_xor(c, off);

  __shared__ float red[4];
  if (lane == 0) red[wave] = c;
  __syncthreads();
  if (threadIdx.x == 0)
    atomicAdd(out, (red[0] + red[1] + red[2] + red[3]) * (1.0f / BATCH));
}

// ---------------------------------------------------------------------------
extern "C" void kernel_launch(void* const* d_in, const int* in_sizes, int n_in,
                              void* d_out, int out_size, void* d_ws, size_t ws_size,
                              hipStream_t stream) {
  const float* ci = (const float*)d_in[0];
  const float* cj = (const float*)d_in[1];
  float* out = (float*)d_out;

  // ws: Li8 u8[B*D] | Qb8 u8[B*D] | hneg f32[B] | isc f32[B] | rowsum f32[B] | diag f32[B]
  unsigned char* Li8 = (unsigned char*)d_ws;
  unsigned char* Qb8 = Li8 + (size_t)BATCH * DIM;
  float* hneg   = (float*)(Qb8 + (size_t)BATCH * DIM);
  float* isc    = hneg + BATCH;
  float* rowsum = isc + BATCH;
  float* diag   = rowsum + BATCH;

  prep_kernel<<<2 * BATCH / 4, 256, 0, stream>>>(ci, cj, Li8, Qb8, hneg, isc, rowsum, out);
  gemm_lse_kernel<<<(BATCH / BM) * (BATCH / BN), 256, 0, stream>>>(Li8, Qb8, hneg, isc, rowsum, diag);
  finalize_kernel<<<BATCH / 256, 256, 0, stream>>>(hneg, rowsum, diag, out);
}